// Round 7
// baseline (68.158 us; speedup 1.0000x reference)
//
#include <hip/hip_runtime.h>

typedef __bf16 bf16x8 __attribute__((ext_vector_type(8)));
typedef float  f32x4  __attribute__((ext_vector_type(4)));
typedef unsigned short u16x8 __attribute__((ext_vector_type(8)));

#define NB 1024
#define NN 128
#define NH 64
#define NOUT 128

__device__ __forceinline__ unsigned short f2b(float f) {
    return __builtin_bit_cast(unsigned short, (__bf16)f);
}

// ---------------- K1: adj fp32 -> bf16 pre-swizzled LDS images in ws ---------
// image byte(b,i,jb) = b*32768 + i*256 + (jb ^ ((i&7)<<4)), jb = 16B chunk off.
// Pure stream: 64 MB read + 32 MB write.
// 2048 blocks x 256 thr x 4 iters x 8 floats = 16,777,216 floats = all of adj.
__global__ __launch_bounds__(256)
void convert_adj(const float* __restrict__ adj, char* __restrict__ ws)
{
    const int g = blockIdx.x * 256 + threadIdx.x;      // 8-float group id base
    #pragma unroll 4
    for (int it = 0; it < 4; ++it) {
        int flat8 = it * 524288 + g;                   // 2048 blk * 256 thr
        const float4* s = (const float4*)adj + (size_t)flat8 * 2;
        float4 a = s[0], c = s[1];
        int b   = flat8 >> 11;                          // 2048 groups / batch
        int rem = flat8 & 2047;
        int i   = rem >> 4;                             // row
        int jb  = (rem & 15) * 16;                      // byte off of 8 bf16
        u16x8 u;
        u[0]=f2b(a.x); u[1]=f2b(a.y); u[2]=f2b(a.z); u[3]=f2b(a.w);
        u[4]=f2b(c.x); u[5]=f2b(c.y); u[6]=f2b(c.z); u[7]=f2b(c.w);
        *(u16x8*)(ws + (size_t)b * 32768 + i * 256 + (jb ^ ((i & 7) << 4))) = u;
    }
}

__device__ __forceinline__ void gload_lds16(const void* g, void* l) {
    __builtin_amdgcn_global_load_lds(
        (const __attribute__((address_space(1))) unsigned int*)g,
        (__attribute__((address_space(3))) unsigned int*)l, 16, 0, 0);
}

// ---------------- K2: per-batch fused GCN ------------------------------------
// 512 threads = 8 waves, 64 KB LDS -> 2 blocks/CU.
// adj_s staged by global_load_lds (linear copy of pre-swizzled image).
// matA/matB identical to round-5-validated layout. Layer 3 = third matA over
// adj_s + cross-lane reduce; out = svec @ W3^T.
__global__ __launch_bounds__(512, 4)
void rsgcn_fused(const int* __restrict__ graph, const char* __restrict__ ws,
                 const float* __restrict__ embed, const float* __restrict__ W1,
                 const float* __restrict__ W2, const float* __restrict__ W3,
                 float* __restrict__ out)
{
    __shared__ __align__(16) char smem[65536];
    char* const adj_s = smem;           // 32768 B (swizzled image)
    char* const hT_s  = smem + 32768;   // 16384 B
    char* const S_s   = smem + 49152;   // 16384 B
    float* const svecp = (float*)S_s;          // [8][64] (S dead in epilogue)
    float* const svec  = (float*)(S_s + 2048); // [64]

    const int b    = blockIdx.x;
    const int t    = threadIdx.x;
    const int lane = t & 63;
    const int wv   = t >> 6;
    const int l15  = lane & 15;
    const int lg   = lane >> 4;

    // ---- stage adj image: 32 KB via global_load_lds (4 x 1KB per wave) ------
    const char* wsb = ws + (size_t)b * 32768;
    #pragma unroll
    for (int q = 0; q < 4; ++q) {
        int chunk = (wv * 4 + q) * 1024;
        gload_lds16(wsb + chunk + lane * 16, adj_s + chunk);
    }

    // ---- embed gather -> hT (packed b64 writes), overlaps the DMA -----------
    {
        const int jq = t & 31;            // nodes 4*jq..+3
        const int d0 = (t >> 5) * 4;      // 4 features
        const int4 g4 = *(const int4*)(graph + b * NN + jq * 4);
        float ea[4][4];
        *(float4*)ea[0] = *(const float4*)(embed + g4.x * NH + d0);
        *(float4*)ea[1] = *(const float4*)(embed + g4.y * NH + d0);
        *(float4*)ea[2] = *(const float4*)(embed + g4.z * NH + d0);
        *(float4*)ea[3] = *(const float4*)(embed + g4.w * NH + d0);
        #pragma unroll
        for (int k = 0; k < 4; ++k) {
            int d = d0 + k;
            ushort4 u;
            u.x = f2b(ea[0][k]); u.y = f2b(ea[1][k]);
            u.z = f2b(ea[2][k]); u.w = f2b(ea[3][k]);
            *(ushort4*)(hT_s + d * 256 + ((jq * 8) ^ ((d & 7) << 4))) = u;
        }
    }
    __syncthreads();   // drains vmcnt (DMA + gather) and lgkm

    // ---- layers 1,2 ----------------------------------------------------------
    const int mtA  = wv & 3;              // matA: d-tile
    const int ntA0 = (wv >> 2) * 4;       // matA: node-tile base
    #pragma unroll
    for (int layer = 0; layer < 2; ++layer) {
        const float* W = layer ? W2 : W1;

        // W B-fragments for this layer (32 VGPRs, L2-resident)
        bf16x8 wf[8];
        #pragma unroll
        for (int nt = 0; nt < 4; ++nt) {
            #pragma unroll
            for (int kk = 0; kk < 2; ++kk) {
                const float4* p = (const float4*)(W + (nt * 16 + l15) * NH
                                                  + kk * 32 + lg * 8);
                float4 v0 = p[0], v1 = p[1];
                bf16x8 a;
                a[0] = (__bf16)v0.x; a[1] = (__bf16)v0.y; a[2] = (__bf16)v0.z; a[3] = (__bf16)v0.w;
                a[4] = (__bf16)v1.x; a[5] = (__bf16)v1.y; a[6] = (__bf16)v1.z; a[7] = (__bf16)v1.w;
                wf[nt * 2 + kk] = a;
            }
        }

        // ---- matA: S^T[d][node] = sum_j hT[d][j] * adj[node][j] --------------
        {
            f32x4 acc[4] = {};
            const int arow = mtA * 16 + l15;
            const int koff = lg * 16;
            #pragma unroll
            for (int kk = 0; kk < 4; ++kk) {
                int kb = kk * 64 + koff;
                bf16x8 af = *(const bf16x8*)(hT_s + arow * 256 + (kb ^ ((arow & 7) << 4)));
                #pragma unroll
                for (int nt = 0; nt < 4; ++nt) {
                    int brow = (ntA0 + nt) * 16 + l15;
                    bf16x8 bfr = *(const bf16x8*)(adj_s + brow * 256 + (kb ^ ((brow & 7) << 4)));
                    acc[nt] = __builtin_amdgcn_mfma_f32_16x16x32_bf16(af, bfr, acc[nt], 0, 0, 0);
                }
            }
            const int dd0 = mtA * 16 + lg * 4;
            #pragma unroll
            for (int nt = 0; nt < 4; ++nt) {
                int node = (ntA0 + nt) * 16 + l15;
                ushort4 u;
                u.x = f2b(acc[nt][0]); u.y = f2b(acc[nt][1]);
                u.z = f2b(acc[nt][2]); u.w = f2b(acc[nt][3]);
                *(ushort4*)(S_s + node * 128 + ((dd0 * 2) ^ ((node & 7) << 4))) = u;
            }
        }
        __syncthreads();

        // ---- matB: h'[node][dout] = relu( sum_d S[node][d] * W[dout][d] ) ----
        {
            f32x4 acc[4] = {};
            const int arow = wv * 16 + l15;       // S row (node)
            const int koff = lg * 16;
            #pragma unroll
            for (int kk = 0; kk < 2; ++kk) {
                int kb = kk * 64 + koff;
                bf16x8 af = *(const bf16x8*)(S_s + arow * 128 + (kb ^ ((arow & 7) << 4)));
                #pragma unroll
                for (int nt = 0; nt < 4; ++nt)
                    acc[nt] = __builtin_amdgcn_mfma_f32_16x16x32_bf16(af, wf[nt * 2 + kk],
                                                                      acc[nt], 0, 0, 0);
            }
            const int node0 = wv * 16 + lg * 4;
            #pragma unroll
            for (int nt = 0; nt < 4; ++nt) {
                int dout = nt * 16 + l15;
                ushort4 u;
                u.x = f2b(fmaxf(acc[nt][0], 0.f)); u.y = f2b(fmaxf(acc[nt][1], 0.f));
                u.z = f2b(fmaxf(acc[nt][2], 0.f)); u.w = f2b(fmaxf(acc[nt][3], 0.f));
                *(ushort4*)(hT_s + dout * 256 + ((node0 * 2) ^ ((dout & 7) << 4))) = u;
            }
        }
        __syncthreads();
    }

    // ---- layer 3: svec[d] = sum_node (adj @ h2)^T[d][node] -------------------
    {
        f32x4 acc3[4] = {};
        const int koff = lg * 16;
        const int brow = wv * 16 + l15;           // this wave's 16 nodes
        #pragma unroll
        for (int kk = 0; kk < 4; ++kk) {
            int kb = kk * 64 + koff;
            bf16x8 bfr = *(const bf16x8*)(adj_s + brow * 256 + (kb ^ ((brow & 7) << 4)));
            #pragma unroll
            for (int dt = 0; dt < 4; ++dt) {
                int arow = dt * 16 + l15;
                bf16x8 ha = *(const bf16x8*)(hT_s + arow * 256 + (kb ^ ((arow & 7) << 4)));
                acc3[dt] = __builtin_amdgcn_mfma_f32_16x16x32_bf16(ha, bfr, acc3[dt], 0, 0, 0);
            }
        }
        // sum over the wave's 16 node-columns (lanes within each lg group)
        #pragma unroll
        for (int m = 1; m <= 8; m <<= 1)
            #pragma unroll
            for (int dt = 0; dt < 4; ++dt)
                #pragma unroll
                for (int i = 0; i < 4; ++i)
                    acc3[dt][i] += __shfl_xor(acc3[dt][i], m);
        if (l15 == 0) {
            #pragma unroll
            for (int dt = 0; dt < 4; ++dt)
                *(f32x4*)(svecp + wv * 64 + dt * 16 + lg * 4) = acc3[dt];
        }
    }
    __syncthreads();

    if (t < 64) {
        float s = 0.f;
        #pragma unroll
        for (int w = 0; w < 8; ++w) s += svecp[w * 64 + t];
        svec[t] = s;
    }
    __syncthreads();

    // ---- out[b][o] = sum_d W3[o][d] * svec[d] (fp32) -------------------------
    if (t < 128) {
        const float4* wrow = (const float4*)(W3 + t * NH);
        float a0 = 0.f, a1 = 0.f;
        #pragma unroll
        for (int q = 0; q < 16; q += 2) {
            float4 w0 = wrow[q], w1 = wrow[q + 1];
            a0 += w0.x*svec[q*4+0] + w0.y*svec[q*4+1] + w0.z*svec[q*4+2] + w0.w*svec[q*4+3];
            a1 += w1.x*svec[q*4+4] + w1.y*svec[q*4+5] + w1.z*svec[q*4+6] + w1.w*svec[q*4+7];
        }
        out[b * NOUT + t] = a0 + a1;
    }
}

extern "C" void kernel_launch(void* const* d_in, const int* in_sizes, int n_in,
                              void* d_out, int out_size, void* d_ws, size_t ws_size,
                              hipStream_t stream) {
    const int*   graph = (const int*)d_in[0];
    const float* adjp  = (const float*)d_in[1];
    const float* embed = (const float*)d_in[2];
    const float* W1    = (const float*)d_in[3];
    const float* W2    = (const float*)d_in[4];
    const float* W3    = (const float*)d_in[5];
    float* outp = (float*)d_out;
    char*  wsb  = (char*)d_ws;   // needs 32 MiB; harness provides ~256 MiB

    convert_adj<<<dim3(2048), dim3(256), 0, stream>>>(adjp, wsb);
    rsgcn_fused<<<dim3(NB), dim3(512), 0, stream>>>(graph, wsb, embed, W1, W2, W3, outp);
}